// Round 1
// baseline (336.337 us; speedup 1.0000x reference)
//
#include <hip/hip_runtime.h>
#include <hip/hip_bf16.h>
#include <cstdint>
#include <cstddef>

// LSTM cell: B=8192, IN=1024, H=1024, fp32 in/out.
// gates[b, g*H+o] = sum_k x[b,k]*Wx[g,o,k] + sum_k h[b,k]*Wh[g,o,k] + bx[g,o] + bh[g,o]
// Strategy: pack [x|h] -> Acat bf16 [8192][2048]; pack [Wx|Wh] -> Wcat bf16 [4096][2048]
// with rows permuted n' = ob*128 + g*32 + ol so a 128-row N-tile holds all 4 gates
// for 32 output columns. GEMM (m97 structure): BM=128,BN=128,BK=64, 4 waves, each
// wave owns 32 rows x 128 cols -> per-lane registers hold i,f,g,o for same (row,col)
// -> fused in-register LSTM epilogue, no gates materialization.

#define B_DIM   8192
#define IN_DIM  1024
#define H_DIM   1024
#define KTOT    2048   // IN + H
#define BK      64     // K per tile step (128 bytes bf16)
#define KSTEPS  (KTOT / BK)   // 32

typedef __attribute__((ext_vector_type(8))) short  bf16x8;
typedef __attribute__((ext_vector_type(4))) float  f32x4;

__device__ __forceinline__ void gld_lds16(const void* g, void* l) {
    __builtin_amdgcn_global_load_lds(
        (const __attribute__((address_space(1))) void*)g,
        (__attribute__((address_space(3))) void*)l, 16, 0, 0);
}

__device__ __forceinline__ unsigned short f2bf(float f) {
    union { float f; unsigned u; } v; v.f = f;
    unsigned r = v.u + 0x7fffu + ((v.u >> 16) & 1u);   // RNE
    return (unsigned short)(r >> 16);
}

// ---- pack [x | h] -> Acat bf16 [8192][2048], row-major ----
__global__ __launch_bounds__(256) void pack_a(const float* __restrict__ x,
                                              const float* __restrict__ h,
                                              unsigned short* __restrict__ Acat) {
    int idx = blockIdx.x * 256 + threadIdx.x;          // 8192*2048/8 = 2097152 chunks
    int row = idx >> 8;                                // 256 chunks of 8 per row
    int k0  = (idx & 255) * 8;
    const float* src = (k0 < IN_DIM) ? (x + (size_t)row * IN_DIM + k0)
                                     : (h + (size_t)row * H_DIM + (k0 - IN_DIM));
    f32x4 v0 = *(const f32x4*)src;
    f32x4 v1 = *(const f32x4*)(src + 4);
    unsigned short tmp[8];
#pragma unroll
    for (int j = 0; j < 4; ++j) tmp[j]     = f2bf(v0[j]);
#pragma unroll
    for (int j = 0; j < 4; ++j) tmp[4 + j] = f2bf(v1[j]);
    *(bf16x8*)(Acat + (size_t)idx * 8) = *(const bf16x8*)tmp;
}

// ---- pack [Wx | Wh] -> Wcat bf16 [4096][2048], rows n' = ob*128 + g*32 + ol ----
__global__ __launch_bounds__(256) void pack_w(const float* __restrict__ Wx,
                                              const float* __restrict__ Wh,
                                              unsigned short* __restrict__ Wcat) {
    int idx = blockIdx.x * 256 + threadIdx.x;          // 4096*2048/8 = 1048576 chunks
    int n   = idx >> 8;
    int k0  = (idx & 255) * 8;
    int ob = n >> 7, g = (n >> 5) & 3, ol = n & 31;
    int o  = ob * 32 + ol;
    const float* src = (k0 < IN_DIM)
        ? (Wx + ((size_t)(g * H_DIM + o)) * IN_DIM + k0)
        : (Wh + ((size_t)(g * H_DIM + o)) * H_DIM + (k0 - IN_DIM));
    f32x4 v0 = *(const f32x4*)src;
    f32x4 v1 = *(const f32x4*)(src + 4);
    unsigned short tmp[8];
#pragma unroll
    for (int j = 0; j < 4; ++j) tmp[j]     = f2bf(v0[j]);
#pragma unroll
    for (int j = 0; j < 4; ++j) tmp[4 + j] = f2bf(v1[j]);
    *(bf16x8*)(Wcat + (size_t)idx * 8) = *(const bf16x8*)tmp;
}

__device__ __forceinline__ float sigmoidf_fast(float v) {
    return 1.0f / (1.0f + __expf(-v));
}

// ---- fused GEMM + LSTM epilogue ----
// grid (32, 64): blockIdx.x = nb (o-block of 32 cols), blockIdx.y = mb (128 B-rows)
__global__ __launch_bounds__(256, 2) void lstm_gemm(
        const unsigned short* __restrict__ Acat,
        const unsigned short* __restrict__ Wcat,
        const float* __restrict__ c,
        const float* __restrict__ bx,
        const float* __restrict__ bh,
        float* __restrict__ outH,
        float* __restrict__ outC) {
    __shared__ __align__(16) char smem[32768];
    char* ldsA = smem;            // 128 rows x 128 bytes (BK=64 bf16), XOR-swizzled
    char* ldsB = smem + 16384;

    const int t    = threadIdx.x;
    const int lane = t & 63;
    const int wid  = t >> 6;
    const int nb   = blockIdx.x;
    const int mb   = blockIdx.y;
    const int m0   = mb * 128;
    const int n0r  = nb * 128;    // row offset in Wcat
    const int l15  = lane & 15;
    const int l4   = lane >> 4;

    f32x4 acc[2][8];
#pragma unroll
    for (int i = 0; i < 2; ++i)
#pragma unroll
        for (int j = 0; j < 8; ++j)
#pragma unroll
            for (int e = 0; e < 4; ++e) acc[i][j][e] = 0.0f;

    const char* Abase = (const char*)Acat;
    const char* Wbase = (const char*)Wcat;

    for (int kt = 0; kt < KSTEPS; ++kt) {
        __syncthreads();                       // previous tile's reads done
        const int kb0 = kt * 128;              // byte offset along K
        // stage A tile: 128x64 bf16 = 16KB; LDS dest linear, global src inverse-swizzled
#pragma unroll
        for (int q = 0; q < 4; ++q) {
            int off  = q * 4096 + t * 16;
            int row  = off >> 7;
            int scol = (off & 127) ^ ((row & 7) << 4);
            gld_lds16(Abase + ((size_t)(m0 + row) * (KTOT * 2) + kb0 + scol), ldsA + off);
        }
#pragma unroll
        for (int q = 0; q < 4; ++q) {
            int off  = q * 4096 + t * 16;
            int row  = off >> 7;
            int scol = (off & 127) ^ ((row & 7) << 4);
            gld_lds16(Wbase + ((size_t)(n0r + row) * (KTOT * 2) + kb0 + scol), ldsB + off);
        }
        __syncthreads();                       // vmcnt drained by compiler before barrier

#pragma unroll
        for (int kk = 0; kk < 2; ++kk) {
            const int kb = kk * 64 + l4 * 16;  // per-lane K byte offset within tile row
            bf16x8 a[2], b[8];
#pragma unroll
            for (int mf = 0; mf < 2; ++mf) {
                int row = wid * 32 + mf * 16 + l15;
                a[mf] = *(const bf16x8*)(ldsA + row * 128 + (kb ^ ((row & 7) << 4)));
            }
#pragma unroll
            for (int nf = 0; nf < 8; ++nf) {
                int row = nf * 16 + l15;
                b[nf] = *(const bf16x8*)(ldsB + row * 128 + (kb ^ ((row & 7) << 4)));
            }
#pragma unroll
            for (int mf = 0; mf < 2; ++mf)
#pragma unroll
                for (int nf = 0; nf < 8; ++nf)
                    acc[mf][nf] = __builtin_amdgcn_mfma_f32_16x16x32_bf16(
                        a[mf], b[nf], acc[mf][nf], 0, 0, 0);
        }
    }

    // ---- fused LSTM epilogue, fully in-register ----
    // C/D frag: col = lane&15, row = (lane>>4)*4 + reg.  nf = 2*gate + half.
#pragma unroll
    for (int hh = 0; hh < 2; ++hh) {
        const int col = nb * 32 + hh * 16 + l15;        // output column (0..1023)
        const float bi = bx[col]            + bh[col];
        const float bf = bx[1024 + col]     + bh[1024 + col];
        const float bg = bx[2048 + col]     + bh[2048 + col];
        const float bo = bx[3072 + col]     + bh[3072 + col];
#pragma unroll
        for (int mf = 0; mf < 2; ++mf) {
#pragma unroll
            for (int j = 0; j < 4; ++j) {
                const int row = m0 + wid * 32 + mf * 16 + l4 * 4 + j;
                const float iv = acc[mf][0 + hh][j] + bi;
                const float fv = acc[mf][2 + hh][j] + bf;
                const float gv = acc[mf][4 + hh][j] + bg;
                const float ov = acc[mf][6 + hh][j] + bo;
                const float ig = sigmoidf_fast(iv);
                const float fg = sigmoidf_fast(fv);
                const float gg = tanhf(gv);
                const float og = sigmoidf_fast(ov);
                const float cin = c[(size_t)row * H_DIM + col];
                const float cn  = fg * cin + ig * gg;
                const float hn  = og * tanhf(cn);
                outH[(size_t)row * H_DIM + col] = hn;
                outC[(size_t)row * H_DIM + col] = cn;
            }
        }
    }
}

extern "C" void kernel_launch(void* const* d_in, const int* in_sizes, int n_in,
                              void* d_out, int out_size, void* d_ws, size_t ws_size,
                              hipStream_t stream) {
    const float* x  = (const float*)d_in[0];
    const float* h  = (const float*)d_in[1];
    const float* c  = (const float*)d_in[2];
    const float* Wx = (const float*)d_in[3];
    const float* bx = (const float*)d_in[4];
    const float* Wh = (const float*)d_in[5];
    const float* bh = (const float*)d_in[6];
    float* out = (float*)d_out;

    unsigned short* Acat = (unsigned short*)d_ws;                       // 32 MB
    unsigned short* Wcat = Acat + (size_t)B_DIM * KTOT;                 // 16 MB

    hipLaunchKernelGGL(pack_a, dim3(8192), dim3(256), 0, stream, x, h, Acat);
    hipLaunchKernelGGL(pack_w, dim3(4096), dim3(256), 0, stream, Wx, Wh, Wcat);
    hipLaunchKernelGGL(lstm_gemm, dim3(32, 64), dim3(256), 0, stream,
                       Acat, Wcat, c, bx, bh,
                       out, out + (size_t)B_DIM * H_DIM);
}

// Round 3
// 300.155 us; speedup vs baseline: 1.1205x; 1.1205x over previous
//
#include <hip/hip_runtime.h>
#include <hip/hip_bf16.h>
#include <cstdint>
#include <cstddef>

// LSTM cell fused as one bf16 GEMM (m201-style 256^2 8-phase schedule) + in-register epilogue.
// A = [x|h] bf16 [8192][2048]. W = [Wx|Wh] bf16 [4096][2048], rows permuted
// n' = (o/16)*64 + g*16 + (o%16)  => a 64-col wave slice = 4 gates x same 16 output cols.
// GEMM: BM=BN=256, BK=64, 512 thr (8 waves 2Mx4N), per-wave 128x64, acc[8][4] f32x4.
// Schedule per K-tile t (4 phases, 2 tiles/unrolled-iter):
//   Ph1: ds_read A(mf0-3,k0)+B(all,k0);  stage B rows128-255 of t+1 -> other buf
//   Ph2: ds_read A(mf0-3,k1)+B(all,k1);  stage A rows'128-255 of t+1 -> other buf
//   Ph3: ds_read A(mf4-7,k0);            stage A rows'0-127  of t+2 -> cur buf (freed after Ph2)
//   Ph4: ds_read A(mf4-7,k1);            stage B rows0-127   of t+2 -> cur buf (freed after Ph2)
//   tile end: s_waitcnt vmcnt(4) when this tile issued its t+2 prefetch (g2), else vmcnt(0).
//   Steady state: 12 outstanding -> retire 8 oldest = exactly all of t+1's data. Tail (g2
//   false): only 8 outstanding and the 4 newest ARE t+1's data -> must drain to 0 (round-2 bug).
// Each phase: [reads+stages] barrier lgkm0 setprio1 16xMFMA setprio0 barrier.

#define B_DIM   8192
#define IN_DIM  1024
#define H_DIM   1024
#define KTOT    2048
#define KROW    4096          // bytes per packed row
#define NT      32            // K-tiles of 64

typedef __attribute__((ext_vector_type(8))) short  bf16x8;
typedef __attribute__((ext_vector_type(4))) float  f32x4;

static __device__ __forceinline__ void gld_lds16(const void* g, void* l) {
    __builtin_amdgcn_global_load_lds(
        (const __attribute__((address_space(1))) void*)g,
        (__attribute__((address_space(3))) void*)l, 16, 0, 0);
}

static __device__ __forceinline__ unsigned short f2bf(float f) {
    union { float f; unsigned u; } v; v.f = f;
    unsigned r = v.u + 0x7fffu + ((v.u >> 16) & 1u);   // RNE
    return (unsigned short)(r >> 16);
}

// ---- fused pack: [x|h] -> Acat ; [Wx|Wh] -> Wcat (permuted rows) ----
__global__ __launch_bounds__(256) void pack_all(const float* __restrict__ x,
                                                const float* __restrict__ h,
                                                const float* __restrict__ Wx,
                                                const float* __restrict__ Wh,
                                                unsigned short* __restrict__ Acat,
                                                unsigned short* __restrict__ Wcat) {
    const int bid = blockIdx.x;
    const float* src;
    unsigned short* dst;
    int idx;
    if (bid < 8192) {                       // A part: 8192*2048/8 chunks
        idx = bid * 256 + threadIdx.x;
        int row = idx >> 8;
        int k0  = (idx & 255) * 8;
        src = (k0 < IN_DIM) ? (x + (size_t)row * IN_DIM + k0)
                            : (h + (size_t)row * H_DIM + (k0 - IN_DIM));
        dst = Acat + (size_t)idx * 8;
    } else {                                // W part: 4096*2048/8 chunks
        idx = (bid - 8192) * 256 + threadIdx.x;
        int n  = idx >> 8;                  // permuted row n'
        int k0 = (idx & 255) * 8;
        int ob64 = n >> 6, g = (n >> 4) & 3, ol = n & 15;
        int o = ob64 * 16 + ol;
        src = (k0 < IN_DIM)
            ? (Wx + (size_t)(g * H_DIM + o) * IN_DIM + k0)
            : (Wh + (size_t)(g * H_DIM + o) * H_DIM + (k0 - IN_DIM));
        dst = Wcat + (size_t)idx * 8;
    }
    f32x4 v0 = *(const f32x4*)src;
    f32x4 v1 = *(const f32x4*)(src + 4);
    unsigned short tmp[8];
#pragma unroll
    for (int j = 0; j < 4; ++j) tmp[j]     = f2bf(v0[j]);
#pragma unroll
    for (int j = 0; j < 4; ++j) tmp[4 + j] = f2bf(v1[j]);
    *(bf16x8*)dst = *(const bf16x8*)tmp;
}

// ---- staging helpers: linear LDS dest, inverse-swizzled global source ----
// A LDS row-permute: rows' = mh*128 + wm*64 + rr  <->  global tile row r = wm*128 + mh*64 + rr
static __device__ __forceinline__ void stageA(const char* Ab, char* lds,
                                              int m0, int kb, int pass, int tid) {
    int off  = pass * 8192 + tid * 16;
    int rowp = off >> 7;
    int scol = (off & 127) ^ ((rowp & 7) << 4);
    int mh = rowp >> 7, wmr = (rowp >> 6) & 1, rr = rowp & 63;
    int r  = wmr * 128 + mh * 64 + rr;
    gld_lds16(Ab + (size_t)(m0 + r) * KROW + kb + scol, lds + off);
}
static __device__ __forceinline__ void stageB(const char* Wb, char* lds,
                                              int n0r, int kb, int pass, int tid) {
    int off  = pass * 8192 + tid * 16;
    int rowp = off >> 7;
    int scol = (off & 127) ^ ((rowp & 7) << 4);
    gld_lds16(Wb + (size_t)(n0r + rowp) * KROW + kb + scol, lds + off);
}

// ---- swizzled ds_read of MFMA fragments ----
static __device__ __forceinline__ bf16x8 ldA(const char* lds, int wm, int mf, int kk,
                                             int l15, int l4) {
    int rowp = (mf >> 2) * 128 + wm * 64 + (mf & 3) * 16 + l15;
    int kb   = kk * 64 + l4 * 16;
    return *(const bf16x8*)(lds + rowp * 128 + (kb ^ ((rowp & 7) << 4)));
}
static __device__ __forceinline__ bf16x8 ldB(const char* lds, int wn, int nf, int kk,
                                             int l15, int l4) {
    int rowp = wn * 64 + nf * 16 + l15;
    int kb   = kk * 64 + l4 * 16;
    return *(const bf16x8*)(lds + rowp * 128 + (kb ^ ((rowp & 7) << 4)));
}

static __device__ __forceinline__ void fence_mem() {
    __builtin_amdgcn_sched_barrier(0);
    asm volatile("" ::: "memory");
}
static __device__ __forceinline__ void phase_barrier() {
    fence_mem();
    __builtin_amdgcn_s_barrier();
    fence_mem();
}

static __device__ __forceinline__ float sigmoid_fast(float v) {
    return 1.0f / (1.0f + __expf(-v));
}
static __device__ __forceinline__ float tanh_fast(float v) {
    return 1.0f - 2.0f / (1.0f + __expf(2.0f * v));
}

// one K-tile: 4 phases
template<int CUR>
static __device__ __forceinline__ void do_tile(
        int t, const char* Ab, const char* Wb,
        char* bufA0, char* bufB0, char* bufA1, char* bufB1,
        f32x4 (&acc)[8][4], bf16x8 (&b)[4][2],
        int m0, int n0r, int tid, int wm, int wn, int l15, int l4) {
    char* cA = CUR ? bufA1 : bufA0;
    char* cB = CUR ? bufB1 : bufB0;
    char* oA = CUR ? bufA0 : bufA1;
    char* oB = CUR ? bufB0 : bufB1;
    const int  kb1 = (t + 1) * 128, kb2 = (t + 2) * 128;
    const bool g1 = (t + 1) < NT, g2 = (t + 2) < NT;
    bf16x8 a[4];

    // ---- Ph1: A(mf0-3,k0) + B(all,k0); stage B rows128-255 of t+1 (other buf) ----
#pragma unroll
    for (int mf = 0; mf < 4; ++mf) a[mf] = ldA(cA, wm, mf, 0, l15, l4);
#pragma unroll
    for (int nf = 0; nf < 4; ++nf) b[nf][0] = ldB(cB, wn, nf, 0, l15, l4);
    if (g1) { stageB(Wb, oB, n0r, kb1, 2, tid); stageB(Wb, oB, n0r, kb1, 3, tid); }
    phase_barrier();
    asm volatile("s_waitcnt lgkmcnt(0)" ::: "memory");
    __builtin_amdgcn_sched_barrier(0);
    __builtin_amdgcn_s_setprio(1);
#pragma unroll
    for (int mf = 0; mf < 4; ++mf)
#pragma unroll
        for (int nf = 0; nf < 4; ++nf)
            acc[mf][nf] = __builtin_amdgcn_mfma_f32_16x16x32_bf16(a[mf], b[nf][0], acc[mf][nf], 0, 0, 0);
    __builtin_amdgcn_s_setprio(0);
    phase_barrier();

    // ---- Ph2: A(mf0-3,k1) + B(all,k1); stage A rows'128-255 of t+1 (other buf) ----
#pragma unroll
    for (int mf = 0; mf < 4; ++mf) a[mf] = ldA(cA, wm, mf, 1, l15, l4);
#pragma unroll
    for (int nf = 0; nf < 4; ++nf) b[nf][1] = ldB(cB, wn, nf, 1, l15, l4);
    if (g1) { stageA(Ab, oA, m0, kb1, 2, tid); stageA(Ab, oA, m0, kb1, 3, tid); }
    phase_barrier();
    asm volatile("s_waitcnt lgkmcnt(0)" ::: "memory");
    __builtin_amdgcn_sched_barrier(0);
    __builtin_amdgcn_s_setprio(1);
#pragma unroll
    for (int mf = 0; mf < 4; ++mf)
#pragma unroll
        for (int nf = 0; nf < 4; ++nf)
            acc[mf][nf] = __builtin_amdgcn_mfma_f32_16x16x32_bf16(a[mf], b[nf][1], acc[mf][nf], 0, 0, 0);
    __builtin_amdgcn_s_setprio(0);
    phase_barrier();

    // ---- Ph3: A(mf4-7,k0); stage A rows'0-127 of t+2 (cur buf; freed after Ph2) ----
#pragma unroll
    for (int mf = 0; mf < 4; ++mf) a[mf] = ldA(cA, wm, 4 + mf, 0, l15, l4);
    if (g2) { stageA(Ab, cA, m0, kb2, 0, tid); stageA(Ab, cA, m0, kb2, 1, tid); }
    phase_barrier();
    asm volatile("s_waitcnt lgkmcnt(0)" ::: "memory");
    __builtin_amdgcn_sched_barrier(0);
    __builtin_amdgcn_s_setprio(1);
#pragma unroll
    for (int mf = 0; mf < 4; ++mf)
#pragma unroll
        for (int nf = 0; nf < 4; ++nf)
            acc[4 + mf][nf] = __builtin_amdgcn_mfma_f32_16x16x32_bf16(a[mf], b[nf][0], acc[4 + mf][nf], 0, 0, 0);
    __builtin_amdgcn_s_setprio(0);
    phase_barrier();

    // ---- Ph4: A(mf4-7,k1); stage B rows0-127 of t+2 (cur buf; freed after Ph2) ----
#pragma unroll
    for (int mf = 0; mf < 4; ++mf) a[mf] = ldA(cA, wm, 4 + mf, 1, l15, l4);
    if (g2) { stageB(Wb, cB, n0r, kb2, 0, tid); stageB(Wb, cB, n0r, kb2, 1, tid); }
    phase_barrier();
    asm volatile("s_waitcnt lgkmcnt(0)" ::: "memory");
    __builtin_amdgcn_sched_barrier(0);
    __builtin_amdgcn_s_setprio(1);
#pragma unroll
    for (int mf = 0; mf < 4; ++mf)
#pragma unroll
        for (int nf = 0; nf < 4; ++nf)
            acc[4 + mf][nf] = __builtin_amdgcn_mfma_f32_16x16x32_bf16(a[mf], b[nf][1], acc[4 + mf][nf], 0, 0, 0);
    __builtin_amdgcn_s_setprio(0);
    // tile end: counted vmcnt. If this tile issued its 4 t+2 prefetch loads (g2),
    // keep exactly those in flight -> retire all of t+1's 8. If not (tail), the
    // 4 newest outstanding loads ARE t+1's data -> must drain fully (round-2 bug fix).
    fence_mem();
    if (g2) { asm volatile("s_waitcnt vmcnt(4)" ::: "memory"); }
    else    { asm volatile("s_waitcnt vmcnt(0)" ::: "memory"); }
    phase_barrier();
}

__global__ __launch_bounds__(512, 2) void lstm_gemm(
        const unsigned short* __restrict__ Acat,
        const unsigned short* __restrict__ Wcat,
        const float* __restrict__ c,
        const float* __restrict__ bx,
        const float* __restrict__ bh,
        float* __restrict__ outH,
        float* __restrict__ outC) {
    __shared__ __align__(16) char smem[131072];
    char* bufA0 = smem;
    char* bufB0 = smem + 32768;
    char* bufA1 = smem + 65536;
    char* bufB1 = smem + 98304;

    const int tid  = threadIdx.x;
    const int lane = tid & 63;
    const int wid  = tid >> 6;
    const int wm   = wid >> 2;          // 0..1
    const int wn   = wid & 3;           // 0..3
    const int l15  = lane & 15;
    const int l4   = lane >> 4;

    const int bid = blockIdx.x;
    const int swz = (bid & 7) * 64 + (bid >> 3);   // XCD-chunked, bijective (512%8==0)
    const int mb  = swz >> 4;           // 0..31
    const int nb  = swz & 15;           // 0..15
    const int m0  = mb * 256;
    const int n0r = nb * 256;

    const char* Ab = (const char*)Acat;
    const char* Wb = (const char*)Wcat;

    f32x4 acc[8][4];
#pragma unroll
    for (int i = 0; i < 8; ++i)
#pragma unroll
        for (int j = 0; j < 4; ++j)
#pragma unroll
            for (int e = 0; e < 4; ++e) acc[i][j][e] = 0.0f;
    bf16x8 b[4][2];

    // ---- prologue: tile0 fully (8 loads) + tile1 early parts (4 loads) ----
#pragma unroll
    for (int p = 0; p < 4; ++p) stageA(Ab, bufA0, m0, 0, p, tid);
#pragma unroll
    for (int p = 0; p < 4; ++p) stageB(Wb, bufB0, n0r, 0, p, tid);
    stageA(Ab, bufA1, m0, 128, 0, tid);
    stageA(Ab, bufA1, m0, 128, 1, tid);
    stageB(Wb, bufB1, n0r, 128, 0, tid);
    stageB(Wb, bufB1, n0r, 128, 1, tid);
    fence_mem();
    asm volatile("s_waitcnt vmcnt(4)" ::: "memory");   // tile0 landed; tile1's 4 in flight
    phase_barrier();

    for (int tt = 0; tt < NT; tt += 2) {
        do_tile<0>(tt,     Ab, Wb, bufA0, bufB0, bufA1, bufB1, acc, b, m0, n0r, tid, wm, wn, l15, l4);
        do_tile<1>(tt + 1, Ab, Wb, bufA0, bufB0, bufA1, bufB1, acc, b, m0, n0r, tid, wm, wn, l15, l4);
    }

    // ---- fused LSTM epilogue, in-register: nf = gate (i,f,g,o) ----
    const int col = (nb * 4 + wn) * 16 + l15;          // output column 0..1023
    const float bi = bx[col]            + bh[col];
    const float bf = bx[1024 + col]     + bh[1024 + col];
    const float bg = bx[2048 + col]     + bh[2048 + col];
    const float bo = bx[3072 + col]     + bh[3072 + col];
#pragma unroll
    for (int mf = 0; mf < 8; ++mf) {
#pragma unroll
        for (int j = 0; j < 4; ++j) {
            const int row = m0 + wm * 128 + mf * 16 + l4 * 4 + j;
            const float iv = acc[mf][0][j] + bi;
            const float fv = acc[mf][1][j] + bf;
            const float gv = acc[mf][2][j] + bg;
            const float ov = acc[mf][3][j] + bo;
            const float ig = sigmoid_fast(iv);
            const float fg = sigmoid_fast(fv);
            const float gg = tanh_fast(gv);
            const float og = sigmoid_fast(ov);
            const float cin = c[(size_t)row * H_DIM + col];
            const float cn  = fg * cin + ig * gg;
            const float hn  = og * tanh_fast(cn);
            outH[(size_t)row * H_DIM + col] = hn;
            outC[(size_t)row * H_DIM + col] = cn;
        }
    }
}

extern "C" void kernel_launch(void* const* d_in, const int* in_sizes, int n_in,
                              void* d_out, int out_size, void* d_ws, size_t ws_size,
                              hipStream_t stream) {
    const float* x  = (const float*)d_in[0];
    const float* h  = (const float*)d_in[1];
    const float* c  = (const float*)d_in[2];
    const float* Wx = (const float*)d_in[3];
    const float* bx = (const float*)d_in[4];
    const float* Wh = (const float*)d_in[5];
    const float* bh = (const float*)d_in[6];
    float* out = (float*)d_out;

    unsigned short* Acat = (unsigned short*)d_ws;                       // 32 MB
    unsigned short* Wcat = Acat + (size_t)B_DIM * KTOT;                 // 16 MB

    hipLaunchKernelGGL(pack_all, dim3(12288), dim3(256), 0, stream, x, h, Wx, Wh, Acat, Wcat);
    hipLaunchKernelGGL(lstm_gemm, dim3(512), dim3(512), 0, stream,
                       Acat, Wcat, c, bx, bh,
                       out, out + (size_t)B_DIM * H_DIM);
}